// Round 1
// baseline (8157.192 us; speedup 1.0000x reference)
//
#include <hip/hip_runtime.h>
#include <hip/hip_bf16.h>

#define N_USERS 100000
#define N_ITEMS 200000
#define N_NODES 300000
#define NNZ_    3000000
#define DIM     64
#define MPHI    1000
#define BATCH_  8192

// ---------------- SpMM: dst[rows[e]] += vals[e] * src[cols[e]] ----------------
// 16 threads per edge, each handles 4 dims via float4 gather + 4 f32 atomics.

__global__ __launch_bounds__(256) void spmm_first_k(
    const int* __restrict__ rows, const int* __restrict__ cols,
    const float* __restrict__ vals,
    const float* __restrict__ uemb, const float* __restrict__ iemb,
    float* __restrict__ dst) {
  int t = blockIdx.x * 256 + threadIdx.x;
  int e = t >> 4;
  if (e >= NNZ_) return;
  int sub = (t & 15) * 4;
  int c = cols[e];
  int r = rows[e];
  float v = vals[e];
  const float* src = (c < N_USERS) ? (uemb + (size_t)c * DIM)
                                   : (iemb + (size_t)(c - N_USERS) * DIM);
  float4 x = *(const float4*)(src + sub);
  float* d = dst + (size_t)r * DIM + sub;
  unsafeAtomicAdd(d + 0, v * x.x);
  unsafeAtomicAdd(d + 1, v * x.y);
  unsafeAtomicAdd(d + 2, v * x.z);
  unsafeAtomicAdd(d + 3, v * x.w);
}

__global__ __launch_bounds__(256) void spmm_k(
    const int* __restrict__ rows, const int* __restrict__ cols,
    const float* __restrict__ vals,
    const float* __restrict__ src, float* __restrict__ dst) {
  int t = blockIdx.x * 256 + threadIdx.x;
  int e = t >> 4;
  if (e >= NNZ_) return;
  int sub = (t & 15) * 4;
  int c = cols[e];
  int r = rows[e];
  float v = vals[e];
  float4 x = *(const float4*)(src + (size_t)c * DIM + sub);
  float* d = dst + (size_t)r * DIM + sub;
  unsafeAtomicAdd(d + 0, v * x.x);
  unsafeAtomicAdd(d + 1, v * x.y);
  unsafeAtomicAdd(d + 2, v * x.z);
  unsafeAtomicAdd(d + 3, v * x.w);
}

// ---------------- selection accumulator: acc_sel[b] = emb[sel[b]] + e1[sel[b]] ----
__global__ __launch_bounds__(256) void init_acc_k(
    const int* __restrict__ users, const int* __restrict__ items,
    const float* __restrict__ uemb, const float* __restrict__ iemb,
    const float* __restrict__ e1, float* __restrict__ acc_sel) {
  int t = blockIdx.x * 256 + threadIdx.x;   // 2*BATCH_*DIM total
  int b = t >> 6, j = t & 63;
  size_t node;
  float base;
  if (b < BATCH_) {
    int u = users[b];
    node = (size_t)u;
    base = uemb[(size_t)u * DIM + j];
  } else {
    int it = items[b - BATCH_];
    node = (size_t)(N_USERS + it);
    base = iemb[(size_t)it * DIM + j];
  }
  acc_sel[t] = base + e1[node * DIM + j];
}

__global__ __launch_bounds__(256) void gather_add_k(
    const int* __restrict__ users, const int* __restrict__ items,
    const float* __restrict__ e, float* __restrict__ acc_sel) {
  int t = blockIdx.x * 256 + threadIdx.x;
  int b = t >> 6, j = t & 63;
  size_t node;
  if (b < BATCH_) node = (size_t)users[b];
  else            node = (size_t)(N_USERS + items[b - BATCH_]);
  acc_sel[t] += e[node * DIM + j];
}

// ---------------- W = phi4 (64x1000) @ ulm_t (1000x64) -> 64x64 --------------
__global__ __launch_bounds__(64) void compute_W_k(
    const float* __restrict__ phi4, const float* __restrict__ ulm_t,
    float* __restrict__ W) {
  int d = blockIdx.x;     // 0..63
  int j = threadIdx.x;    // 0..63
  float s = 0.f;
  for (int k = 0; k < MPHI; k += 4) {
    float4 p = *(const float4*)(phi4 + (size_t)d * MPHI + k);
    s += p.x * ulm_t[(k + 0) * DIM + j];
    s += p.y * ulm_t[(k + 1) * DIM + j];
    s += p.z * ulm_t[(k + 2) * DIM + j];
    s += p.w * ulm_t[(k + 3) * DIM + j];
  }
  W[d * DIM + j] = s;
}

// ---------------- final: out[b] = 0.5*gamma_id + gamma_lm --------------------
// one wave (64 lanes = 64 dims) per batch element, 4 waves per block
__global__ __launch_bounds__(256) void final_k(
    const int* __restrict__ users, const int* __restrict__ items,
    const float* __restrict__ acc_sel,
    const float* __restrict__ phi3, const float* __restrict__ phi2,
    const float* __restrict__ ulm_t, const float* __restrict__ item_lm,
    const float* __restrict__ W, float* __restrict__ out) {
  __shared__ float Ws[DIM * DIM];
  int tid = threadIdx.x;
  for (int i = tid; i < DIM * DIM; i += 256) Ws[i] = W[i];
  __syncthreads();
  int wave = tid >> 6, lane = tid & 63;
  int b = blockIdx.x * 4 + wave;
  if (b >= BATCH_) return;
  int u = users[b], it = items[b];

  // gamma_id: dot(acc_u, acc_i) / 16  (light_out = acc/4 on both sides)
  float au = acc_sel[(size_t)b * DIM + lane];
  float ai = acc_sel[(size_t)(BATCH_ + b) * DIM + lane];
  float gid = au * ai * (1.0f / 16.0f);

  // lm path: user_lm[lane] = 0.1 * (phi3[u] @ W)[lane] + 0.9 * (phi2[u] @ ulm_t)[lane]
  const float* p3 = phi3 + (size_t)u * DIM;
  float w3 = 0.f;
#pragma unroll
  for (int d2 = 0; d2 < DIM; d2++) w3 += p3[d2] * Ws[d2 * DIM + lane];

  const float* p2 = phi2 + (size_t)u * MPHI;
  float w2 = 0.f;
  for (int k = 0; k < MPHI; k += 4) {
    float4 p = *(const float4*)(p2 + k);
    w2 += p.x * ulm_t[(k + 0) * DIM + lane];
    w2 += p.y * ulm_t[(k + 1) * DIM + lane];
    w2 += p.z * ulm_t[(k + 2) * DIM + lane];
    w2 += p.w * ulm_t[(k + 3) * DIM + lane];
  }
  float il = item_lm[(size_t)it * DIM + lane];
  float val = gid * 0.5f + (0.1f * w3 + 0.9f * w2) * il;

  // wave reduction (64 lanes)
#pragma unroll
  for (int o = 32; o > 0; o >>= 1) val += __shfl_xor(val, o, 64);
  if (lane == 0) out[b] = val;
}

extern "C" void kernel_launch(void* const* d_in, const int* in_sizes, int n_in,
                              void* d_out, int out_size, void* d_ws, size_t ws_size,
                              hipStream_t stream) {
  const int*   users    = (const int*)d_in[0];
  const int*   items    = (const int*)d_in[1];
  const float* user_emb = (const float*)d_in[2];
  const float* item_emb = (const float*)d_in[3];
  const int*   rows     = (const int*)d_in[4];
  const int*   cols     = (const int*)d_in[5];
  const float* vals     = (const float*)d_in[6];
  const float* phi3     = (const float*)d_in[7];
  const float* phi4     = (const float*)d_in[8];
  const float* phi2     = (const float*)d_in[9];
  const float* ulm_t    = (const float*)d_in[10];
  const float* item_lm  = (const float*)d_in[11];
  float* out = (float*)d_out;

  float* buf0    = (float*)d_ws;
  float* buf1    = buf0 + (size_t)N_NODES * DIM;
  float* acc_sel = buf1 + (size_t)N_NODES * DIM;
  float* W       = acc_sel + (size_t)2 * BATCH_ * DIM;

  size_t ebytes = (size_t)N_NODES * DIM * sizeof(float);
  int spmmGrid = (NNZ_ * 16 + 255) / 256;
  int selGrid  = (2 * BATCH_ * DIM) / 256;

  // W = phi4 @ ulm_t (independent, tiny)
  compute_W_k<<<64, 64, 0, stream>>>(phi4, ulm_t, W);

  // layer 1: e1 = A @ all_emb  -> buf0
  hipMemsetAsync(buf0, 0, ebytes, stream);
  spmm_first_k<<<spmmGrid, 256, 0, stream>>>(rows, cols, vals, user_emb, item_emb, buf0);
  init_acc_k<<<selGrid, 256, 0, stream>>>(users, items, user_emb, item_emb, buf0, acc_sel);

  // layer 2: e2 = A @ e1 -> buf1
  hipMemsetAsync(buf1, 0, ebytes, stream);
  spmm_k<<<spmmGrid, 256, 0, stream>>>(rows, cols, vals, buf0, buf1);
  gather_add_k<<<selGrid, 256, 0, stream>>>(users, items, buf1, acc_sel);

  // layer 3: e3 = A @ e2 -> buf0
  hipMemsetAsync(buf0, 0, ebytes, stream);
  spmm_k<<<spmmGrid, 256, 0, stream>>>(rows, cols, vals, buf1, buf0);
  gather_add_k<<<selGrid, 256, 0, stream>>>(users, items, buf0, acc_sel);

  // final fused gamma
  final_k<<<(BATCH_ + 3) / 4, 256, 0, stream>>>(users, items, acc_sel, phi3, phi2,
                                                ulm_t, item_lm, W, out);
}

// Round 2
// 1163.172 us; speedup vs baseline: 7.0129x; 7.0129x over previous
//
#include <hip/hip_runtime.h>
#include <hip/hip_bf16.h>

#define N_USERS 100000
#define N_ITEMS 200000
#define N_NODES 300000
#define NNZ_    3000000
#define DIM     64
#define MPHI    1000
#define BATCH_  8192
#define NB_SCAN 1172   // ceil(N_NODES/256)

// ===================== CSR build =====================

__global__ __launch_bounds__(256) void hist_k(const int* __restrict__ rows,
                                              int* __restrict__ counts) {
  int e = blockIdx.x * 256 + threadIdx.x;
  if (e < NNZ_) atomicAdd(&counts[rows[e]], 1);
}

// per-256-chunk scan: tmp_excl[i] = exclusive scan within chunk; blk_sums[b] = chunk total
__global__ __launch_bounds__(256) void scan_blk_k(const int* __restrict__ counts,
                                                  int* __restrict__ tmp_excl,
                                                  int* __restrict__ blk_sums) {
  __shared__ int s[2][256];
  int t = threadIdx.x;
  int i = blockIdx.x * 256 + t;
  int v = (i < N_NODES) ? counts[i] : 0;
  int pi = 0;
  s[0][t] = v;
  __syncthreads();
#pragma unroll
  for (int o = 1; o < 256; o <<= 1) {
    int x = s[pi][t] + ((t >= o) ? s[pi][t - o] : 0);
    s[pi ^ 1][t] = x;
    __syncthreads();
    pi ^= 1;
  }
  int incl = s[pi][t];
  if (i < N_NODES) tmp_excl[i] = incl - v;
  if (t == 255) blk_sums[blockIdx.x] = incl;
}

// single-block exclusive scan over blk_sums[0..NB_SCAN)
__global__ __launch_bounds__(256) void scan_sums_k(int* __restrict__ blk_sums) {
  __shared__ int s[2][256];
  __shared__ int carry;
  int t = threadIdx.x;
  if (t == 0) carry = 0;
  __syncthreads();
  for (int base = 0; base < NB_SCAN; base += 256) {
    int i = base + t;
    int v = (i < NB_SCAN) ? blk_sums[i] : 0;
    int pi = 0;
    s[0][t] = v;
    __syncthreads();
#pragma unroll
    for (int o = 1; o < 256; o <<= 1) {
      int x = s[pi][t] + ((t >= o) ? s[pi][t - o] : 0);
      s[pi ^ 1][t] = x;
      __syncthreads();
      pi ^= 1;
    }
    int incl = s[pi][t];
    if (i < NB_SCAN) blk_sums[i] = carry + incl - v;  // exclusive
    __syncthreads();
    if (t == 255) carry += incl;  // incl of lane 255 == chunk total
    __syncthreads();
  }
}

__global__ __launch_bounds__(256) void finalize_rowptr_k(const int* __restrict__ tmp_excl,
                                                         const int* __restrict__ blk_sums,
                                                         int* __restrict__ row_ptr,
                                                         int* __restrict__ row_off) {
  int i = blockIdx.x * 256 + threadIdx.x;
  if (i < N_NODES) {
    int v = tmp_excl[i] + blk_sums[i >> 8];
    row_ptr[i] = v;
    row_off[i] = v;
  }
  if (i == 0) row_ptr[N_NODES] = NNZ_;
}

__global__ __launch_bounds__(256) void scatter_k(const int* __restrict__ rows,
                                                 const int* __restrict__ cols,
                                                 const float* __restrict__ vals,
                                                 int* __restrict__ row_off,
                                                 int2* __restrict__ cvs) {
  int e = blockIdx.x * 256 + threadIdx.x;
  if (e >= NNZ_) return;
  int r = rows[e];
  int pos = atomicAdd(&row_off[r], 1);
  cvs[pos] = make_int2(cols[e], __float_as_int(vals[e]));
}

// ===================== concat all_emb =====================
__global__ __launch_bounds__(256) void concat_k(const float4* __restrict__ u,
                                                const float4* __restrict__ it,
                                                float4* __restrict__ dst) {
  int i = blockIdx.x * 256 + threadIdx.x;  // exactly N_NODES*16
  const int NU4 = N_USERS * 16;
  dst[i] = (i < NU4) ? u[i] : it[i - NU4];
}

// ===================== CSR SpMM: one wave (64 lanes = 64 dims) per row =====================
__global__ __launch_bounds__(256) void spmm_csr_k(const int* __restrict__ row_ptr,
                                                  const int2* __restrict__ cvs,
                                                  const float* __restrict__ src,
                                                  float* __restrict__ dst) {
  int r = blockIdx.x * 4 + (threadIdx.x >> 6);  // grid sized exactly
  int lane = threadIdx.x & 63;
  int beg = row_ptr[r], end = row_ptr[r + 1];
  float acc = 0.f;
  int e = beg;
  for (; e + 4 <= end; e += 4) {
    int2 c0 = cvs[e], c1 = cvs[e + 1], c2 = cvs[e + 2], c3 = cvs[e + 3];
    float x0 = src[(size_t)c0.x * DIM + lane];
    float x1 = src[(size_t)c1.x * DIM + lane];
    float x2 = src[(size_t)c2.x * DIM + lane];
    float x3 = src[(size_t)c3.x * DIM + lane];
    acc = fmaf(__int_as_float(c0.y), x0, acc);
    acc = fmaf(__int_as_float(c1.y), x1, acc);
    acc = fmaf(__int_as_float(c2.y), x2, acc);
    acc = fmaf(__int_as_float(c3.y), x3, acc);
  }
  for (; e < end; e++) {
    int2 c = cvs[e];
    acc = fmaf(__int_as_float(c.y), src[(size_t)c.x * DIM + lane], acc);
  }
  dst[(size_t)r * DIM + lane] = acc;
}

// layer-3: only the 16384 selected rows, accumulate straight into acc_sel
__global__ __launch_bounds__(256) void spmm_sel_k(const int* __restrict__ users,
                                                  const int* __restrict__ items,
                                                  const int* __restrict__ row_ptr,
                                                  const int2* __restrict__ cvs,
                                                  const float* __restrict__ src,
                                                  float* __restrict__ acc_sel) {
  int w = blockIdx.x * 4 + (threadIdx.x >> 6);  // 0..2*BATCH_-1
  int lane = threadIdx.x & 63;
  int node = (w < BATCH_) ? users[w] : N_USERS + items[w - BATCH_];
  int beg = row_ptr[node], end = row_ptr[node + 1];
  float acc = 0.f;
  int e = beg;
  for (; e + 4 <= end; e += 4) {
    int2 c0 = cvs[e], c1 = cvs[e + 1], c2 = cvs[e + 2], c3 = cvs[e + 3];
    float x0 = src[(size_t)c0.x * DIM + lane];
    float x1 = src[(size_t)c1.x * DIM + lane];
    float x2 = src[(size_t)c2.x * DIM + lane];
    float x3 = src[(size_t)c3.x * DIM + lane];
    acc = fmaf(__int_as_float(c0.y), x0, acc);
    acc = fmaf(__int_as_float(c1.y), x1, acc);
    acc = fmaf(__int_as_float(c2.y), x2, acc);
    acc = fmaf(__int_as_float(c3.y), x3, acc);
  }
  for (; e < end; e++) {
    int2 c = cvs[e];
    acc = fmaf(__int_as_float(c.y), src[(size_t)c.x * DIM + lane], acc);
  }
  acc_sel[(size_t)w * DIM + lane] += acc;
}

// acc_sel[b] = all_emb[sel[b]] + e1[sel[b]]
__global__ __launch_bounds__(256) void init_acc2_k(const int* __restrict__ users,
                                                   const int* __restrict__ items,
                                                   const float* __restrict__ allemb,
                                                   const float* __restrict__ e1,
                                                   float* __restrict__ acc_sel) {
  int t = blockIdx.x * 256 + threadIdx.x;
  int b = t >> 6, j = t & 63;
  size_t node = (b < BATCH_) ? (size_t)users[b] : (size_t)(N_USERS + items[b - BATCH_]);
  size_t idx = node * DIM + j;
  acc_sel[t] = allemb[idx] + e1[idx];
}

__global__ __launch_bounds__(256) void gather_add_k(const int* __restrict__ users,
                                                    const int* __restrict__ items,
                                                    const float* __restrict__ e,
                                                    float* __restrict__ acc_sel) {
  int t = blockIdx.x * 256 + threadIdx.x;
  int b = t >> 6, j = t & 63;
  size_t node = (b < BATCH_) ? (size_t)users[b] : (size_t)(N_USERS + items[b - BATCH_]);
  acc_sel[t] += e[node * DIM + j];
}

// ===================== fallback atomic SpMM (round-1 path) =====================
__global__ __launch_bounds__(256) void spmm_first_k(const int* __restrict__ rows,
                                                    const int* __restrict__ cols,
                                                    const float* __restrict__ vals,
                                                    const float* __restrict__ uemb,
                                                    const float* __restrict__ iemb,
                                                    float* __restrict__ dst) {
  int t = blockIdx.x * 256 + threadIdx.x;
  int e = t >> 4;
  if (e >= NNZ_) return;
  int sub = (t & 15) * 4;
  int c = cols[e];
  int r = rows[e];
  float v = vals[e];
  const float* src = (c < N_USERS) ? (uemb + (size_t)c * DIM)
                                   : (iemb + (size_t)(c - N_USERS) * DIM);
  float4 x = *(const float4*)(src + sub);
  float* d = dst + (size_t)r * DIM + sub;
  unsafeAtomicAdd(d + 0, v * x.x);
  unsafeAtomicAdd(d + 1, v * x.y);
  unsafeAtomicAdd(d + 2, v * x.z);
  unsafeAtomicAdd(d + 3, v * x.w);
}

__global__ __launch_bounds__(256) void spmm_k(const int* __restrict__ rows,
                                              const int* __restrict__ cols,
                                              const float* __restrict__ vals,
                                              const float* __restrict__ src,
                                              float* __restrict__ dst) {
  int t = blockIdx.x * 256 + threadIdx.x;
  int e = t >> 4;
  if (e >= NNZ_) return;
  int sub = (t & 15) * 4;
  int c = cols[e];
  int r = rows[e];
  float v = vals[e];
  float4 x = *(const float4*)(src + (size_t)c * DIM + sub);
  float* d = dst + (size_t)r * DIM + sub;
  unsafeAtomicAdd(d + 0, v * x.x);
  unsafeAtomicAdd(d + 1, v * x.y);
  unsafeAtomicAdd(d + 2, v * x.z);
  unsafeAtomicAdd(d + 3, v * x.w);
}

__global__ __launch_bounds__(256) void init_acc_k(const int* __restrict__ users,
                                                  const int* __restrict__ items,
                                                  const float* __restrict__ uemb,
                                                  const float* __restrict__ iemb,
                                                  const float* __restrict__ e1,
                                                  float* __restrict__ acc_sel) {
  int t = blockIdx.x * 256 + threadIdx.x;
  int b = t >> 6, j = t & 63;
  size_t node;
  float base;
  if (b < BATCH_) {
    int u = users[b];
    node = (size_t)u;
    base = uemb[(size_t)u * DIM + j];
  } else {
    int it = items[b - BATCH_];
    node = (size_t)(N_USERS + it);
    base = iemb[(size_t)it * DIM + j];
  }
  acc_sel[t] = base + e1[node * DIM + j];
}

// ===================== W = phi4 @ ulm_t =====================
__global__ __launch_bounds__(64) void compute_W_k(const float* __restrict__ phi4,
                                                  const float* __restrict__ ulm_t,
                                                  float* __restrict__ W) {
  int d = blockIdx.x;
  int j = threadIdx.x;
  float s = 0.f;
  for (int k = 0; k < MPHI; k += 4) {
    float4 p = *(const float4*)(phi4 + (size_t)d * MPHI + k);
    s += p.x * ulm_t[(k + 0) * DIM + j];
    s += p.y * ulm_t[(k + 1) * DIM + j];
    s += p.z * ulm_t[(k + 2) * DIM + j];
    s += p.w * ulm_t[(k + 3) * DIM + j];
  }
  W[d * DIM + j] = s;
}

// ===================== final gamma =====================
__global__ __launch_bounds__(256) void final_k(const int* __restrict__ users,
                                               const int* __restrict__ items,
                                               const float* __restrict__ acc_sel,
                                               const float* __restrict__ phi3,
                                               const float* __restrict__ phi2,
                                               const float* __restrict__ ulm_t,
                                               const float* __restrict__ item_lm,
                                               const float* __restrict__ W,
                                               float* __restrict__ out) {
  __shared__ float Ws[DIM * DIM];
  int tid = threadIdx.x;
  for (int i = tid; i < DIM * DIM; i += 256) Ws[i] = W[i];
  __syncthreads();
  int wave = tid >> 6, lane = tid & 63;
  int b = blockIdx.x * 4 + wave;
  if (b >= BATCH_) return;
  int u = users[b], it = items[b];

  float au = acc_sel[(size_t)b * DIM + lane];
  float ai = acc_sel[(size_t)(BATCH_ + b) * DIM + lane];
  float gid = au * ai * (1.0f / 16.0f);

  const float* p3 = phi3 + (size_t)u * DIM;
  float w3 = 0.f;
#pragma unroll
  for (int d2 = 0; d2 < DIM; d2++) w3 += p3[d2] * Ws[d2 * DIM + lane];

  const float* p2 = phi2 + (size_t)u * MPHI;
  float w2 = 0.f;
  for (int k = 0; k < MPHI; k += 4) {
    float4 p = *(const float4*)(p2 + k);
    w2 += p.x * ulm_t[(k + 0) * DIM + lane];
    w2 += p.y * ulm_t[(k + 1) * DIM + lane];
    w2 += p.z * ulm_t[(k + 2) * DIM + lane];
    w2 += p.w * ulm_t[(k + 3) * DIM + lane];
  }
  float il = item_lm[(size_t)it * DIM + lane];
  float val = gid * 0.5f + (0.1f * w3 + 0.9f * w2) * il;

#pragma unroll
  for (int o = 32; o > 0; o >>= 1) val += __shfl_xor(val, o, 64);
  if (lane == 0) out[b] = val;
}

extern "C" void kernel_launch(void* const* d_in, const int* in_sizes, int n_in,
                              void* d_out, int out_size, void* d_ws, size_t ws_size,
                              hipStream_t stream) {
  const int*   users    = (const int*)d_in[0];
  const int*   items    = (const int*)d_in[1];
  const float* user_emb = (const float*)d_in[2];
  const float* item_emb = (const float*)d_in[3];
  const int*   rows     = (const int*)d_in[4];
  const int*   cols     = (const int*)d_in[5];
  const float* vals     = (const float*)d_in[6];
  const float* phi3     = (const float*)d_in[7];
  const float* phi4     = (const float*)d_in[8];
  const float* phi2     = (const float*)d_in[9];
  const float* ulm_t    = (const float*)d_in[10];
  const float* item_lm  = (const float*)d_in[11];
  float* out = (float*)d_out;

  // CSR-path workspace layout
  size_t o = 0;
  auto take = [&](size_t bytes) { size_t cur = o; o = (o + bytes + 255) & ~(size_t)255; return cur; };
  size_t off_buf0 = take((size_t)N_NODES * DIM * 4);
  size_t off_buf1 = take((size_t)N_NODES * DIM * 4);
  size_t off_acc  = take((size_t)2 * BATCH_ * DIM * 4);
  size_t off_W    = take((size_t)DIM * DIM * 4);
  size_t off_rp   = take((size_t)(N_NODES + 1) * 4);
  size_t off_cnt  = take((size_t)N_NODES * 4);
  size_t off_tmp  = take((size_t)N_NODES * 4);
  size_t off_roff = take((size_t)N_NODES * 4);
  size_t off_bs   = take((size_t)(NB_SCAN + 16) * 4);
  size_t off_cvs  = take((size_t)NNZ_ * 8);
  size_t need = o;

  char* base = (char*)d_ws;
  int selGrid = (2 * BATCH_ * DIM) / 256;

  if (ws_size >= need) {
    // ---------------- CSR path ----------------
    float* buf0    = (float*)(base + off_buf0);
    float* buf1    = (float*)(base + off_buf1);
    float* acc_sel = (float*)(base + off_acc);
    float* W       = (float*)(base + off_W);
    int*   row_ptr = (int*)(base + off_rp);
    int*   counts  = (int*)(base + off_cnt);
    int*   tmp     = (int*)(base + off_tmp);
    int*   row_off = (int*)(base + off_roff);
    int*   blk_sums= (int*)(base + off_bs);
    int2*  cvs     = (int2*)(base + off_cvs);

    int edgeGrid = (NNZ_ + 255) / 256;

    compute_W_k<<<64, 64, 0, stream>>>(phi4, ulm_t, W);

    // build CSR
    hipMemsetAsync(counts, 0, (size_t)N_NODES * 4, stream);
    hist_k<<<edgeGrid, 256, 0, stream>>>(rows, counts);
    scan_blk_k<<<NB_SCAN, 256, 0, stream>>>(counts, tmp, blk_sums);
    scan_sums_k<<<1, 256, 0, stream>>>(blk_sums);
    finalize_rowptr_k<<<NB_SCAN, 256, 0, stream>>>(tmp, blk_sums, row_ptr, row_off);
    scatter_k<<<edgeGrid, 256, 0, stream>>>(rows, cols, vals, row_off, cvs);

    // buf0 = all_emb
    concat_k<<<(N_NODES * 16) / 256, 256, 0, stream>>>((const float4*)user_emb,
                                                       (const float4*)item_emb,
                                                       (float4*)buf0);
    // layer 1: buf0 -> buf1 ; acc = buf0_sel + buf1_sel
    spmm_csr_k<<<N_NODES / 4, 256, 0, stream>>>(row_ptr, cvs, buf0, buf1);
    init_acc2_k<<<selGrid, 256, 0, stream>>>(users, items, buf0, buf1, acc_sel);
    // layer 2: buf1 -> buf0 ; acc += buf0_sel
    spmm_csr_k<<<N_NODES / 4, 256, 0, stream>>>(row_ptr, cvs, buf1, buf0);
    gather_add_k<<<selGrid, 256, 0, stream>>>(users, items, buf0, acc_sel);
    // layer 3: selected rows only, from buf0 (e2), accumulate into acc_sel
    spmm_sel_k<<<(2 * BATCH_) / 4, 256, 0, stream>>>(users, items, row_ptr, cvs, buf0, acc_sel);

    final_k<<<BATCH_ / 4, 256, 0, stream>>>(users, items, acc_sel, phi3, phi2,
                                            ulm_t, item_lm, W, out);
  } else {
    // ---------------- fallback: round-1 atomic path ----------------
    float* buf0    = (float*)d_ws;
    float* buf1    = buf0 + (size_t)N_NODES * DIM;
    float* acc_sel = buf1 + (size_t)N_NODES * DIM;
    float* W       = acc_sel + (size_t)2 * BATCH_ * DIM;

    size_t ebytes = (size_t)N_NODES * DIM * sizeof(float);
    int spmmGrid = (NNZ_ * 16 + 255) / 256;

    compute_W_k<<<64, 64, 0, stream>>>(phi4, ulm_t, W);

    hipMemsetAsync(buf0, 0, ebytes, stream);
    spmm_first_k<<<spmmGrid, 256, 0, stream>>>(rows, cols, vals, user_emb, item_emb, buf0);
    init_acc_k<<<selGrid, 256, 0, stream>>>(users, items, user_emb, item_emb, buf0, acc_sel);

    hipMemsetAsync(buf1, 0, ebytes, stream);
    spmm_k<<<spmmGrid, 256, 0, stream>>>(rows, cols, vals, buf0, buf1);
    gather_add_k<<<selGrid, 256, 0, stream>>>(users, items, buf1, acc_sel);

    hipMemsetAsync(buf0, 0, ebytes, stream);
    spmm_k<<<spmmGrid, 256, 0, stream>>>(rows, cols, vals, buf1, buf0);
    gather_add_k<<<selGrid, 256, 0, stream>>>(users, items, buf0, acc_sel);

    final_k<<<BATCH_ / 4, 256, 0, stream>>>(users, items, acc_sel, phi3, phi2,
                                            ulm_t, item_lm, W, out);
  }
}

// Round 3
// 775.516 us; speedup vs baseline: 10.5184x; 1.4999x over previous
//
#include <hip/hip_runtime.h>
#include <hip/hip_bf16.h>

#define N_USERS 100000
#define N_ITEMS 200000
#define N_NODES 300000
#define NNZ_    3000000
#define DIM     64
#define MPHI    1000
#define BATCH_  8192
#define NB_SCAN 1172   // ceil(N_NODES/256)
#define TBROW   32     // batch rows per w2_gemm block

// ===================== CSR build =====================

__global__ __launch_bounds__(256) void hist_k(const int* __restrict__ rows,
                                              int* __restrict__ counts) {
  int e = blockIdx.x * 256 + threadIdx.x;
  if (e < NNZ_) atomicAdd(&counts[rows[e]], 1);
}

__global__ __launch_bounds__(256) void scan_blk_k(const int* __restrict__ counts,
                                                  int* __restrict__ tmp_excl,
                                                  int* __restrict__ blk_sums) {
  __shared__ int s[2][256];
  int t = threadIdx.x;
  int i = blockIdx.x * 256 + t;
  int v = (i < N_NODES) ? counts[i] : 0;
  int pi = 0;
  s[0][t] = v;
  __syncthreads();
#pragma unroll
  for (int o = 1; o < 256; o <<= 1) {
    int x = s[pi][t] + ((t >= o) ? s[pi][t - o] : 0);
    s[pi ^ 1][t] = x;
    __syncthreads();
    pi ^= 1;
  }
  int incl = s[pi][t];
  if (i < N_NODES) tmp_excl[i] = incl - v;
  if (t == 255) blk_sums[blockIdx.x] = incl;
}

__global__ __launch_bounds__(256) void scan_sums_k(int* __restrict__ blk_sums) {
  __shared__ int s[2][256];
  __shared__ int carry;
  int t = threadIdx.x;
  if (t == 0) carry = 0;
  __syncthreads();
  for (int base = 0; base < NB_SCAN; base += 256) {
    int i = base + t;
    int v = (i < NB_SCAN) ? blk_sums[i] : 0;
    int pi = 0;
    s[0][t] = v;
    __syncthreads();
#pragma unroll
    for (int o = 1; o < 256; o <<= 1) {
      int x = s[pi][t] + ((t >= o) ? s[pi][t - o] : 0);
      s[pi ^ 1][t] = x;
      __syncthreads();
      pi ^= 1;
    }
    int incl = s[pi][t];
    if (i < NB_SCAN) blk_sums[i] = carry + incl - v;
    __syncthreads();
    if (t == 255) carry += incl;
    __syncthreads();
  }
}

__global__ __launch_bounds__(256) void finalize_rowptr_k(const int* __restrict__ tmp_excl,
                                                         const int* __restrict__ blk_sums,
                                                         int* __restrict__ row_ptr,
                                                         int* __restrict__ row_off) {
  int i = blockIdx.x * 256 + threadIdx.x;
  if (i < N_NODES) {
    int v = tmp_excl[i] + blk_sums[i >> 8];
    row_ptr[i] = v;
    row_off[i] = v;
  }
  if (i == 0) row_ptr[N_NODES] = NNZ_;
}

__global__ __launch_bounds__(256) void scatter_k(const int* __restrict__ rows,
                                                 const int* __restrict__ cols,
                                                 const float* __restrict__ vals,
                                                 int* __restrict__ row_off,
                                                 int2* __restrict__ cvs) {
  int e = blockIdx.x * 256 + threadIdx.x;
  if (e >= NNZ_) return;
  int r = rows[e];
  int pos = atomicAdd(&row_off[r], 1);
  cvs[pos] = make_int2(cols[e], __float_as_int(vals[e]));
}

// ===================== concat all_emb =====================
__global__ __launch_bounds__(256) void concat_k(const float4* __restrict__ u,
                                                const float4* __restrict__ it,
                                                float4* __restrict__ dst) {
  int i = blockIdx.x * 256 + threadIdx.x;
  const int NU4 = N_USERS * 16;
  dst[i] = (i < NU4) ? u[i] : it[i - NU4];
}

// ===================== CSR SpMM: one wave per row =====================
__global__ __launch_bounds__(256) void spmm_csr_k(const int* __restrict__ row_ptr,
                                                  const int2* __restrict__ cvs,
                                                  const float* __restrict__ src,
                                                  float* __restrict__ dst) {
  int r = blockIdx.x * 4 + (threadIdx.x >> 6);
  int lane = threadIdx.x & 63;
  int beg = row_ptr[r], end = row_ptr[r + 1];
  float acc = 0.f;
  int e = beg;
  for (; e + 4 <= end; e += 4) {
    int2 c0 = cvs[e], c1 = cvs[e + 1], c2 = cvs[e + 2], c3 = cvs[e + 3];
    float x0 = src[(size_t)c0.x * DIM + lane];
    float x1 = src[(size_t)c1.x * DIM + lane];
    float x2 = src[(size_t)c2.x * DIM + lane];
    float x3 = src[(size_t)c3.x * DIM + lane];
    acc = fmaf(__int_as_float(c0.y), x0, acc);
    acc = fmaf(__int_as_float(c1.y), x1, acc);
    acc = fmaf(__int_as_float(c2.y), x2, acc);
    acc = fmaf(__int_as_float(c3.y), x3, acc);
  }
  for (; e < end; e++) {
    int2 c = cvs[e];
    acc = fmaf(__int_as_float(c.y), src[(size_t)c.x * DIM + lane], acc);
  }
  dst[(size_t)r * DIM + lane] = acc;
}

// layer-3: only selected rows, accumulate into acc_sel
__global__ __launch_bounds__(256) void spmm_sel_k(const int* __restrict__ users,
                                                  const int* __restrict__ items,
                                                  const int* __restrict__ row_ptr,
                                                  const int2* __restrict__ cvs,
                                                  const float* __restrict__ src,
                                                  float* __restrict__ acc_sel) {
  int w = blockIdx.x * 4 + (threadIdx.x >> 6);
  int lane = threadIdx.x & 63;
  int node = (w < BATCH_) ? users[w] : N_USERS + items[w - BATCH_];
  int beg = row_ptr[node], end = row_ptr[node + 1];
  float acc = 0.f;
  int e = beg;
  for (; e + 4 <= end; e += 4) {
    int2 c0 = cvs[e], c1 = cvs[e + 1], c2 = cvs[e + 2], c3 = cvs[e + 3];
    float x0 = src[(size_t)c0.x * DIM + lane];
    float x1 = src[(size_t)c1.x * DIM + lane];
    float x2 = src[(size_t)c2.x * DIM + lane];
    float x3 = src[(size_t)c3.x * DIM + lane];
    acc = fmaf(__int_as_float(c0.y), x0, acc);
    acc = fmaf(__int_as_float(c1.y), x1, acc);
    acc = fmaf(__int_as_float(c2.y), x2, acc);
    acc = fmaf(__int_as_float(c3.y), x3, acc);
  }
  for (; e < end; e++) {
    int2 c = cvs[e];
    acc = fmaf(__int_as_float(c.y), src[(size_t)c.x * DIM + lane], acc);
  }
  acc_sel[(size_t)w * DIM + lane] += acc;
}

__global__ __launch_bounds__(256) void init_acc2_k(const int* __restrict__ users,
                                                   const int* __restrict__ items,
                                                   const float* __restrict__ allemb,
                                                   const float* __restrict__ e1,
                                                   float* __restrict__ acc_sel) {
  int t = blockIdx.x * 256 + threadIdx.x;
  int b = t >> 6, j = t & 63;
  size_t node = (b < BATCH_) ? (size_t)users[b] : (size_t)(N_USERS + items[b - BATCH_]);
  size_t idx = node * DIM + j;
  acc_sel[t] = allemb[idx] + e1[idx];
}

__global__ __launch_bounds__(256) void gather_add_k(const int* __restrict__ users,
                                                    const int* __restrict__ items,
                                                    const float* __restrict__ e,
                                                    float* __restrict__ acc_sel) {
  int t = blockIdx.x * 256 + threadIdx.x;
  int b = t >> 6, j = t & 63;
  size_t node = (b < BATCH_) ? (size_t)users[b] : (size_t)(N_USERS + items[b - BATCH_]);
  acc_sel[t] += e[node * DIM + j];
}

// ===================== W = phi4 @ ulm_t (4 waves split k) =====================
__global__ __launch_bounds__(256) void compute_W_k(const float* __restrict__ phi4,
                                                   const float* __restrict__ ulm_t,
                                                   float* __restrict__ W) {
  __shared__ float part[4][64];
  int d = blockIdx.x;
  int lane = threadIdx.x & 63, w = threadIdx.x >> 6;
  float s = 0.f;
  int k0 = w * 250, k1 = k0 + 250;
  for (int k = k0; k < k1; k++)
    s = fmaf(phi4[(size_t)d * MPHI + k], ulm_t[(size_t)k * DIM + lane], s);
  part[w][lane] = s;
  __syncthreads();
  if (w == 0)
    W[d * DIM + lane] = part[0][lane] + part[1][lane] + part[2][lane] + part[3][lane];
}

// ===================== user_lm GEMM: [0.9*phi2 | 0.1*phi3] @ [ulm_t ; W] =====================
// grid 256 blocks x 256 threads; block computes 32 batch rows x 64 cols.
__global__ __launch_bounds__(256) void w2_gemm_k(const int* __restrict__ users,
                                                 const float* __restrict__ phi2,
                                                 const float* __restrict__ phi3,
                                                 const float* __restrict__ ulm_t,
                                                 const float* __restrict__ W,
                                                 float* __restrict__ wlm) {
  __shared__ float u_s[64][68];
  __shared__ float p_s[TBROW][68];
  int tid = threadIdx.x;
  int j = tid & 63;
  int g = tid >> 6;            // 0..3 -> rows g*8..g*8+7
  int b0 = blockIdx.x * TBROW;

  float acc[8];
#pragma unroll
  for (int i = 0; i < 8; i++) acc[i] = 0.f;

  for (int chunk = 0; chunk < 17; chunk++) {
    int kc = chunk * 64;
    bool lm = (chunk == 16);
    // stage u_s: ulm_t rows kc..kc+63 (zero past MPHI), or W for the lm chunk
    for (int idx = tid; idx < 64 * 16; idx += 256) {
      int kk = idx >> 4, c4 = (idx & 15) << 2;
      float4 v = make_float4(0.f, 0.f, 0.f, 0.f);
      if (lm) v = *(const float4*)(W + (size_t)kk * DIM + c4);
      else if (kc + kk < MPHI) v = *(const float4*)(ulm_t + (size_t)(kc + kk) * DIM + c4);
      *(float4*)&u_s[kk][c4] = v;
    }
    // stage p_s: 0.9*phi2 rows (gathered), or 0.1*phi3 for the lm chunk
    for (int idx = tid; idx < TBROW * 16; idx += 256) {
      int row = idx >> 4, c4 = (idx & 15) << 2;
      int u = users[b0 + row];
      float4 v = make_float4(0.f, 0.f, 0.f, 0.f);
      if (lm) {
        v = *(const float4*)(phi3 + (size_t)u * DIM + c4);
        v.x *= 0.1f; v.y *= 0.1f; v.z *= 0.1f; v.w *= 0.1f;
      } else if (kc + c4 < MPHI) {
        v = *(const float4*)(phi2 + (size_t)u * MPHI + kc + c4);
        v.x *= 0.9f; v.y *= 0.9f; v.z *= 0.9f; v.w *= 0.9f;
      }
      *(float4*)&p_s[row][c4] = v;
    }
    __syncthreads();
#pragma unroll
    for (int kk = 0; kk < 64; kk += 4) {
      float u0 = u_s[kk + 0][j];
      float u1 = u_s[kk + 1][j];
      float u2 = u_s[kk + 2][j];
      float u3 = u_s[kk + 3][j];
#pragma unroll
      for (int i = 0; i < 8; i++) {
        float4 p = *(const float4*)&p_s[g * 8 + i][kk];
        acc[i] = fmaf(p.w, u3, fmaf(p.z, u2, fmaf(p.y, u1, fmaf(p.x, u0, acc[i]))));
      }
    }
    __syncthreads();
  }
#pragma unroll
  for (int i = 0; i < 8; i++)
    wlm[(size_t)(b0 + g * 8 + i) * DIM + j] = acc[i];
}

// ===================== final gamma (reads precomputed wlm) =====================
__global__ __launch_bounds__(256) void final2_k(const int* __restrict__ items,
                                                const float* __restrict__ acc_sel,
                                                const float* __restrict__ wlm,
                                                const float* __restrict__ item_lm,
                                                float* __restrict__ out) {
  int tid = threadIdx.x;
  int wave = tid >> 6, lane = tid & 63;
  int b = blockIdx.x * 4 + wave;
  int it = items[b];
  float au = acc_sel[(size_t)b * DIM + lane];
  float ai = acc_sel[(size_t)(BATCH_ + b) * DIM + lane];
  float val = au * ai * (0.5f / 16.0f) +
              wlm[(size_t)b * DIM + lane] * item_lm[(size_t)it * DIM + lane];
#pragma unroll
  for (int o = 32; o > 0; o >>= 1) val += __shfl_xor(val, o, 64);
  if (lane == 0) out[b] = val;
}

// ===================== fallback atomic path (round-1) =====================
__global__ __launch_bounds__(256) void spmm_first_k(const int* __restrict__ rows,
                                                    const int* __restrict__ cols,
                                                    const float* __restrict__ vals,
                                                    const float* __restrict__ uemb,
                                                    const float* __restrict__ iemb,
                                                    float* __restrict__ dst) {
  int t = blockIdx.x * 256 + threadIdx.x;
  int e = t >> 4;
  if (e >= NNZ_) return;
  int sub = (t & 15) * 4;
  int c = cols[e];
  int r = rows[e];
  float v = vals[e];
  const float* src = (c < N_USERS) ? (uemb + (size_t)c * DIM)
                                   : (iemb + (size_t)(c - N_USERS) * DIM);
  float4 x = *(const float4*)(src + sub);
  float* d = dst + (size_t)r * DIM + sub;
  unsafeAtomicAdd(d + 0, v * x.x);
  unsafeAtomicAdd(d + 1, v * x.y);
  unsafeAtomicAdd(d + 2, v * x.z);
  unsafeAtomicAdd(d + 3, v * x.w);
}

__global__ __launch_bounds__(256) void spmm_k(const int* __restrict__ rows,
                                              const int* __restrict__ cols,
                                              const float* __restrict__ vals,
                                              const float* __restrict__ src,
                                              float* __restrict__ dst) {
  int t = blockIdx.x * 256 + threadIdx.x;
  int e = t >> 4;
  if (e >= NNZ_) return;
  int sub = (t & 15) * 4;
  int c = cols[e];
  int r = rows[e];
  float v = vals[e];
  float4 x = *(const float4*)(src + (size_t)c * DIM + sub);
  float* d = dst + (size_t)r * DIM + sub;
  unsafeAtomicAdd(d + 0, v * x.x);
  unsafeAtomicAdd(d + 1, v * x.y);
  unsafeAtomicAdd(d + 2, v * x.z);
  unsafeAtomicAdd(d + 3, v * x.w);
}

__global__ __launch_bounds__(256) void init_acc_k(const int* __restrict__ users,
                                                  const int* __restrict__ items,
                                                  const float* __restrict__ uemb,
                                                  const float* __restrict__ iemb,
                                                  const float* __restrict__ e1,
                                                  float* __restrict__ acc_sel) {
  int t = blockIdx.x * 256 + threadIdx.x;
  int b = t >> 6, j = t & 63;
  size_t node;
  float base;
  if (b < BATCH_) {
    int u = users[b];
    node = (size_t)u;
    base = uemb[(size_t)u * DIM + j];
  } else {
    int it = items[b - BATCH_];
    node = (size_t)(N_USERS + it);
    base = iemb[(size_t)it * DIM + j];
  }
  acc_sel[t] = base + e1[node * DIM + j];
}

__global__ __launch_bounds__(256) void final_k(const int* __restrict__ users,
                                               const int* __restrict__ items,
                                               const float* __restrict__ acc_sel,
                                               const float* __restrict__ phi3,
                                               const float* __restrict__ phi2,
                                               const float* __restrict__ ulm_t,
                                               const float* __restrict__ item_lm,
                                               const float* __restrict__ W,
                                               float* __restrict__ out) {
  __shared__ float Ws[DIM * DIM];
  int tid = threadIdx.x;
  for (int i = tid; i < DIM * DIM; i += 256) Ws[i] = W[i];
  __syncthreads();
  int wave = tid >> 6, lane = tid & 63;
  int b = blockIdx.x * 4 + wave;
  if (b >= BATCH_) return;
  int u = users[b], it = items[b];
  float au = acc_sel[(size_t)b * DIM + lane];
  float ai = acc_sel[(size_t)(BATCH_ + b) * DIM + lane];
  float gid = au * ai * (1.0f / 16.0f);
  const float* p3 = phi3 + (size_t)u * DIM;
  float w3 = 0.f;
#pragma unroll
  for (int d2 = 0; d2 < DIM; d2++) w3 += p3[d2] * Ws[d2 * DIM + lane];
  const float* p2 = phi2 + (size_t)u * MPHI;
  float w2 = 0.f;
  for (int k = 0; k < MPHI; k += 4) {
    float4 p = *(const float4*)(p2 + k);
    w2 += p.x * ulm_t[(k + 0) * DIM + lane];
    w2 += p.y * ulm_t[(k + 1) * DIM + lane];
    w2 += p.z * ulm_t[(k + 2) * DIM + lane];
    w2 += p.w * ulm_t[(k + 3) * DIM + lane];
  }
  float il = item_lm[(size_t)it * DIM + lane];
  float val = gid * 0.5f + (0.1f * w3 + 0.9f * w2) * il;
#pragma unroll
  for (int o = 32; o > 0; o >>= 1) val += __shfl_xor(val, o, 64);
  if (lane == 0) out[b] = val;
}

extern "C" void kernel_launch(void* const* d_in, const int* in_sizes, int n_in,
                              void* d_out, int out_size, void* d_ws, size_t ws_size,
                              hipStream_t stream) {
  const int*   users    = (const int*)d_in[0];
  const int*   items    = (const int*)d_in[1];
  const float* user_emb = (const float*)d_in[2];
  const float* item_emb = (const float*)d_in[3];
  const int*   rows     = (const int*)d_in[4];
  const int*   cols     = (const int*)d_in[5];
  const float* vals     = (const float*)d_in[6];
  const float* phi3     = (const float*)d_in[7];
  const float* phi4     = (const float*)d_in[8];
  const float* phi2     = (const float*)d_in[9];
  const float* ulm_t    = (const float*)d_in[10];
  const float* item_lm  = (const float*)d_in[11];
  float* out = (float*)d_out;

  size_t o = 0;
  auto take = [&](size_t bytes) { size_t cur = o; o = (o + bytes + 255) & ~(size_t)255; return cur; };
  size_t off_buf0 = take((size_t)N_NODES * DIM * 4);
  size_t off_buf1 = take((size_t)N_NODES * DIM * 4);
  size_t off_acc  = take((size_t)2 * BATCH_ * DIM * 4);
  size_t off_W    = take((size_t)DIM * DIM * 4);
  size_t off_rp   = take((size_t)(N_NODES + 1) * 4);
  size_t off_cnt  = take((size_t)N_NODES * 4);
  size_t off_tmp  = take((size_t)N_NODES * 4);
  size_t off_roff = take((size_t)N_NODES * 4);
  size_t off_bs   = take((size_t)(NB_SCAN + 16) * 4);
  size_t off_cvs  = take((size_t)NNZ_ * 8);
  size_t need = o;

  char* base = (char*)d_ws;
  int selGrid = (2 * BATCH_ * DIM) / 256;

  if (ws_size >= need) {
    float* buf0    = (float*)(base + off_buf0);
    float* buf1    = (float*)(base + off_buf1);
    float* acc_sel = (float*)(base + off_acc);
    float* W       = (float*)(base + off_W);
    int*   row_ptr = (int*)(base + off_rp);
    int*   counts  = (int*)(base + off_cnt);
    int*   tmp     = (int*)(base + off_tmp);
    int*   row_off = (int*)(base + off_roff);
    int*   blk_sums= (int*)(base + off_bs);
    int2*  cvs     = (int2*)(base + off_cvs);
    float* wlm     = buf1;   // buf1 is dead after layer-2 spmm; alias for the LM GEMM output

    int edgeGrid = (NNZ_ + 255) / 256;

    compute_W_k<<<64, 256, 0, stream>>>(phi4, ulm_t, W);

    hipMemsetAsync(counts, 0, (size_t)N_NODES * 4, stream);
    hist_k<<<edgeGrid, 256, 0, stream>>>(rows, counts);
    scan_blk_k<<<NB_SCAN, 256, 0, stream>>>(counts, tmp, blk_sums);
    scan_sums_k<<<1, 256, 0, stream>>>(blk_sums);
    finalize_rowptr_k<<<NB_SCAN, 256, 0, stream>>>(tmp, blk_sums, row_ptr, row_off);
    scatter_k<<<edgeGrid, 256, 0, stream>>>(rows, cols, vals, row_off, cvs);

    concat_k<<<(N_NODES * 16) / 256, 256, 0, stream>>>((const float4*)user_emb,
                                                       (const float4*)item_emb,
                                                       (float4*)buf0);
    // layer 1
    spmm_csr_k<<<N_NODES / 4, 256, 0, stream>>>(row_ptr, cvs, buf0, buf1);
    init_acc2_k<<<selGrid, 256, 0, stream>>>(users, items, buf0, buf1, acc_sel);
    // layer 2
    spmm_csr_k<<<N_NODES / 4, 256, 0, stream>>>(row_ptr, cvs, buf1, buf0);
    gather_add_k<<<selGrid, 256, 0, stream>>>(users, items, buf0, acc_sel);
    // buf1 dead: LM GEMM into it
    w2_gemm_k<<<BATCH_ / TBROW, 256, 0, stream>>>(users, phi2, phi3, ulm_t, W, wlm);
    // layer 3 (selected rows only)
    spmm_sel_k<<<(2 * BATCH_) / 4, 256, 0, stream>>>(users, items, row_ptr, cvs, buf0, acc_sel);

    final2_k<<<BATCH_ / 4, 256, 0, stream>>>(items, acc_sel, wlm, item_lm, out);
  } else {
    float* buf0    = (float*)d_ws;
    float* buf1    = buf0 + (size_t)N_NODES * DIM;
    float* acc_sel = buf1 + (size_t)N_NODES * DIM;
    float* W       = acc_sel + (size_t)2 * BATCH_ * DIM;

    size_t ebytes = (size_t)N_NODES * DIM * sizeof(float);
    int spmmGrid = (NNZ_ * 16 + 255) / 256;

    compute_W_k<<<64, 256, 0, stream>>>(phi4, ulm_t, W);

    hipMemsetAsync(buf0, 0, ebytes, stream);
    spmm_first_k<<<spmmGrid, 256, 0, stream>>>(rows, cols, vals, user_emb, item_emb, buf0);
    init_acc_k<<<selGrid, 256, 0, stream>>>(users, items, user_emb, item_emb, buf0, acc_sel);

    hipMemsetAsync(buf1, 0, ebytes, stream);
    spmm_k<<<spmmGrid, 256, 0, stream>>>(rows, cols, vals, buf0, buf1);
    gather_add_k<<<selGrid, 256, 0, stream>>>(users, items, buf1, acc_sel);

    hipMemsetAsync(buf0, 0, ebytes, stream);
    spmm_k<<<spmmGrid, 256, 0, stream>>>(rows, cols, vals, buf1, buf0);
    gather_add_k<<<selGrid, 256, 0, stream>>>(users, items, buf0, acc_sel);

    final_k<<<BATCH_ / 4, 256, 0, stream>>>(users, items, acc_sel, phi3, phi2,
                                            ulm_t, item_lm, W, out);
  }
}